// Round 1
// baseline (1373.360 us; speedup 1.0000x reference)
//
#include <hip/hip_runtime.h>
#include <cstdint>

#define B_   2
#define L_   2048
#define D_   512
#define H_   8
#define DH_  64
#define DFC_ 2048

// workspace layout in floats
#define Q_OFF    0u
#define K_OFF    2097152u
#define V_OFF    4194304u
#define ATTN_OFF 8388608u   // attn output (B,L,D)
#define HID_OFF  0u         // ffn hidden reuses dead q/k/v region
// total ws: (8388608 + 2097152) * 4 B = 41.94 MB

__device__ __forceinline__ unsigned short f32_bf16(float f) {
  unsigned u = __float_as_uint(f);
  u += 0x7FFFu + ((u >> 16) & 1u);   // round-to-nearest-even
  return (unsigned short)(u >> 16);
}
__device__ __forceinline__ float bf16lo_f32(unsigned u) { return __uint_as_float(u << 16); }
__device__ __forceinline__ float bf16hi_f32(unsigned u) { return __uint_as_float(u & 0xFFFF0000u); }

// ---------------------------------------------------------------------------
// f32 tiled GEMM: C = A(MxK) @ B(KxN) + bias, 64x64 tile, 256 thr, 4x4/thread
// MODE 0: bias; MODE 1: bias+relu; MODE 2: bias + scatter to (B,H,L,DH)
// ---------------------------------------------------------------------------
template <int MODE>
__global__ __launch_bounds__(256)
void gemm_f32(const float* __restrict__ A, const float* __restrict__ Bw,
              const float* __restrict__ bias, float* __restrict__ C,
              int M, int N, int K) {
  __shared__ float As[16 * 68];   // A^T tile: As[kk][m], stride 68 (16B-aligned rows)
  __shared__ float Bs[16 * 64];   // Bs[kk][n]
  const int t  = threadIdx.x;
  const int tx = t & 15, ty = t >> 4;
  const int n0 = blockIdx.x * 64, m0 = blockIdx.y * 64;

  float acc[4][4] = {};

  for (int k0 = 0; k0 < K; k0 += 16) {
    {
      const int kk = t & 15, mb = t >> 4;
#pragma unroll
      for (int it = 0; it < 4; ++it) {
        int m = mb + it * 16;
        As[kk * 68 + m] = A[(size_t)(m0 + m) * K + k0 + kk];
      }
    }
    {
      const int n = t & 63, kbase = t >> 6;
#pragma unroll
      for (int it = 0; it < 4; ++it) {
        int kk = kbase + it * 4;
        Bs[kk * 64 + n] = Bw[(size_t)(k0 + kk) * N + n0 + n];
      }
    }
    __syncthreads();
#pragma unroll
    for (int kk = 0; kk < 16; ++kk) {
      float4 av = *(const float4*)&As[kk * 68 + ty * 4];
      float4 bv = *(const float4*)&Bs[kk * 64 + tx * 4];
      float a[4] = {av.x, av.y, av.z, av.w};
      float b[4] = {bv.x, bv.y, bv.z, bv.w};
#pragma unroll
      for (int i = 0; i < 4; ++i)
#pragma unroll
        for (int j = 0; j < 4; ++j)
          acc[i][j] = fmaf(a[i], b[j], acc[i][j]);
    }
    __syncthreads();
  }

  if (MODE == 2) {
#pragma unroll
    for (int i = 0; i < 4; ++i) {
      int r = m0 + ty * 4 + i;
      int b = r >> 11, l = r & (L_ - 1);
#pragma unroll
      for (int j = 0; j < 4; ++j) {
        int c = n0 + tx * 4 + j;
        int h = c >> 6, dh = c & 63;
        C[((size_t)(b * H_ + h) * L_ + l) * DH_ + dh] = acc[i][j] + bias[c];
      }
    }
  } else {
    const float* bp = bias + n0 + tx * 4;
    float b0 = bp[0], b1 = bp[1], b2 = bp[2], b3 = bp[3];
#pragma unroll
    for (int i = 0; i < 4; ++i) {
      int r = m0 + ty * 4 + i;
      float4 o;
      o.x = acc[i][0] + b0; o.y = acc[i][1] + b1;
      o.z = acc[i][2] + b2; o.w = acc[i][3] + b3;
      if (MODE == 1) {
        o.x = fmaxf(o.x, 0.f); o.y = fmaxf(o.y, 0.f);
        o.z = fmaxf(o.z, 0.f); o.w = fmaxf(o.w, 0.f);
      }
      *(float4*)&C[(size_t)r * N + n0 + tx * 4] = o;
    }
  }
}

// ---------------------------------------------------------------------------
// Flash-style relative attention. Grid (L/64, B*H). 64 q-rows per block.
// s[i,j] = (q[i]·(k[j] + e[L-1-i+j])) / 8 ; causal; online softmax; O = P·V.
// thread t: row r = t>>2 (0..63), col-group cg = t&3 (16 cols / 16 dh each).
// ---------------------------------------------------------------------------
__global__ __launch_bounds__(256)
void attn_kernel(const float* __restrict__ q, const float* __restrict__ k,
                 const float* __restrict__ v, const float* __restrict__ rel,
                 float* __restrict__ attn) {
  __shared__ float qsT[64 * 64];   // q transposed: qsT[d][ii]
  __shared__ float kp[64 * 68];    // k rows (stride 68); later P rows (stride 68)
  __shared__ float esv[64 * 68];   // e band as bf16 (127 rows, stride 66 shorts); later V rows f32 stride 68
  unsigned short* es = (unsigned short*)esv;

  const int t  = threadIdx.x;
  const int qb = blockIdx.x;
  const int bh = blockIdx.y;
  const int h  = bh & (H_ - 1);
  const int i0 = qb * 64;
  const int r  = t >> 2;
  const int cg = t & 3;

  const float* qptr = q + (size_t)bh * L_ * DH_;
  const float* kptr = k + (size_t)bh * L_ * DH_;
  const float* vptr = v + (size_t)bh * L_ * DH_;

  for (int idx = t; idx < 64 * 16; idx += 256) {
    int ii = idx >> 4, d4 = (idx & 15) * 4;
    float4 f = *(const float4*)&qptr[(size_t)(i0 + ii) * DH_ + d4];
    qsT[(d4 + 0) * 64 + ii] = f.x;
    qsT[(d4 + 1) * 64 + ii] = f.y;
    qsT[(d4 + 2) * 64 + ii] = f.z;
    qsT[(d4 + 3) * 64 + ii] = f.w;
  }

  float m_r = -INFINITY, l_r = 0.f;
  float O[16];
#pragma unroll
  for (int i = 0; i < 16; ++i) O[i] = 0.f;

  for (int kb = 0; kb <= qb; ++kb) {
    const int j0 = kb * 64;
    __syncthreads();   // prior O-phase done with kp/esv
    // stage K tile
    for (int idx = t; idx < 64 * 16; idx += 256) {
      int j = idx >> 4, d4 = (idx & 15) * 4;
      *(float4*)&kp[j * 68 + d4] =
          *(const float4*)&kptr[(size_t)(j0 + j) * DH_ + d4];
    }
    // stage e band (127 rows), bf16, stride 66 shorts
    const int m_lo = L_ - 64 - i0 + j0;
    for (int idx = t; idx < 127 * 16; idx += 256) {
      int row = idx >> 4, d4 = (idx & 15) * 4;
      int m = m_lo + row; if (m > L_ - 1) m = L_ - 1;   // clamped rows are masked anyway
      float4 f = *(const float4*)&rel[(size_t)m * D_ + h * DH_ + d4];
      unsigned lo = (unsigned)f32_bf16(f.x) | ((unsigned)f32_bf16(f.y) << 16);
      unsigned hi = (unsigned)f32_bf16(f.z) | ((unsigned)f32_bf16(f.w) << 16);
      *(unsigned*)&es[row * 66 + d4]     = lo;
      *(unsigned*)&es[row * 66 + d4 + 2] = hi;
    }
    __syncthreads();

    // s = q · (k + e_shifted)
    float s[16];
#pragma unroll
    for (int i = 0; i < 16; ++i) s[i] = 0.f;
#pragma unroll 2
    for (int d = 0; d < 64; d += 4) {
      float q0 = qsT[(d + 0) * 64 + r];
      float q1 = qsT[(d + 1) * 64 + r];
      float q2 = qsT[(d + 2) * 64 + r];
      float q3 = qsT[(d + 3) * 64 + r];
#pragma unroll
      for (int qq = 0; qq < 16; ++qq) {
        int jj = cg * 16 + qq;
        int bi = 63 + jj - r;           // e-band row for (r, jj)
        float4 kf = *(const float4*)&kp[jj * 68 + d];
        unsigned e01 = *(const unsigned*)&es[bi * 66 + d];
        unsigned e23 = *(const unsigned*)&es[bi * 66 + d + 2];
        s[qq] = fmaf(q0, kf.x + bf16lo_f32(e01), s[qq]);
        s[qq] = fmaf(q1, kf.y + bf16hi_f32(e01), s[qq]);
        s[qq] = fmaf(q2, kf.z + bf16lo_f32(e23), s[qq]);
        s[qq] = fmaf(q3, kf.w + bf16hi_f32(e23), s[qq]);
      }
    }

    const bool diag = (kb == qb);
    float mymax = -INFINITY;
#pragma unroll
    for (int qq = 0; qq < 16; ++qq) {
      int jj = cg * 16 + qq;
      float val = s[qq] * 0.125f;
      if (diag && jj > r) val = -1e30f;   // causal mask
      s[qq] = val;
      mymax = fmaxf(mymax, val);
    }
    mymax = fmaxf(mymax, __shfl_xor(mymax, 1));
    mymax = fmaxf(mymax, __shfl_xor(mymax, 2));
    float m_new = fmaxf(m_r, mymax);
    float alpha = __expf(m_r - m_new);
    float psum = 0.f;
#pragma unroll
    for (int qq = 0; qq < 16; ++qq) {
      float p = __expf(s[qq] - m_new);
      s[qq] = p;
      psum += p;
    }
    psum += __shfl_xor(psum, 1);
    psum += __shfl_xor(psum, 2);
    l_r = l_r * alpha + psum;
    m_r = m_new;
#pragma unroll
    for (int i = 0; i < 16; ++i) O[i] *= alpha;

    __syncthreads();   // everyone done reading kp(k)/es(e)
    // write P into kp region; stage V into esv region (f32, stride 68)
#pragma unroll
    for (int qq = 0; qq < 16; ++qq) kp[r * 68 + cg * 16 + qq] = s[qq];
    for (int idx = t; idx < 64 * 16; idx += 256) {
      int j = idx >> 4, d4 = (idx & 15) * 4;
      *(float4*)&esv[j * 68 + d4] =
          *(const float4*)&vptr[(size_t)(j0 + j) * DH_ + d4];
    }
    __syncthreads();

    // O += P · V
#pragma unroll 4
    for (int j = 0; j < 64; ++j) {
      float pv = kp[r * 68 + j];
      const float* vrow = &esv[j * 68 + cg * 16];
      float4 v0 = *(const float4*)&vrow[0];
      float4 v1 = *(const float4*)&vrow[4];
      float4 v2 = *(const float4*)&vrow[8];
      float4 v3 = *(const float4*)&vrow[12];
      O[0]  = fmaf(pv, v0.x, O[0]);  O[1]  = fmaf(pv, v0.y, O[1]);
      O[2]  = fmaf(pv, v0.z, O[2]);  O[3]  = fmaf(pv, v0.w, O[3]);
      O[4]  = fmaf(pv, v1.x, O[4]);  O[5]  = fmaf(pv, v1.y, O[5]);
      O[6]  = fmaf(pv, v1.z, O[6]);  O[7]  = fmaf(pv, v1.w, O[7]);
      O[8]  = fmaf(pv, v2.x, O[8]);  O[9]  = fmaf(pv, v2.y, O[9]);
      O[10] = fmaf(pv, v2.z, O[10]); O[11] = fmaf(pv, v2.w, O[11]);
      O[12] = fmaf(pv, v3.x, O[12]); O[13] = fmaf(pv, v3.y, O[13]);
      O[14] = fmaf(pv, v3.z, O[14]); O[15] = fmaf(pv, v3.w, O[15]);
    }
  }

  // epilogue: write attn[b][l][h*64 + dh], normalized
  float inv_l = 1.f / l_r;
  int b = bh >> 3;
  float* orow = attn + ((size_t)(b * L_ + i0 + r) * D_) + h * DH_ + cg * 16;
#pragma unroll
  for (int g = 0; g < 4; ++g) {
    float4 o;
    o.x = O[g * 4 + 0] * inv_l; o.y = O[g * 4 + 1] * inv_l;
    o.z = O[g * 4 + 2] * inv_l; o.w = O[g * 4 + 3] * inv_l;
    *(float4*)&orow[g * 4] = o;
  }
}

// ---------------------------------------------------------------------------
extern "C" void kernel_launch(void* const* d_in, const int* in_sizes, int n_in,
                              void* d_out, int out_size, void* d_ws, size_t ws_size,
                              hipStream_t stream) {
  const float* x   = (const float*)d_in[0];
  // d_in[1] = mask (unused; causal mask applied analytically)
  const float* wq  = (const float*)d_in[2];
  const float* bq  = (const float*)d_in[3];
  const float* wk  = (const float*)d_in[4];
  const float* bk  = (const float*)d_in[5];
  const float* wv  = (const float*)d_in[6];
  const float* bv  = (const float*)d_in[7];
  const float* rel = (const float*)d_in[8];
  const float* w1  = (const float*)d_in[9];
  const float* b1  = (const float*)d_in[10];
  const float* w2  = (const float*)d_in[11];
  const float* b2  = (const float*)d_in[12];

  float* ws   = (float*)d_ws;
  float* qbuf = ws + Q_OFF;
  float* kbuf = ws + K_OFF;
  float* vbuf = ws + V_OFF;
  float* attn = ws + ATTN_OFF;
  float* hid  = ws + HID_OFF;
  float* out  = (float*)d_out;

  dim3 blk(256);
  // QKV projections: (B*L,512) @ (512,512) -> scatter (B,H,L,DH)
  gemm_f32<2><<<dim3(8, 64), blk, 0, stream>>>(x, wq, bq, qbuf, B_ * L_, D_, D_);
  gemm_f32<2><<<dim3(8, 64), blk, 0, stream>>>(x, wk, bk, kbuf, B_ * L_, D_, D_);
  gemm_f32<2><<<dim3(8, 64), blk, 0, stream>>>(x, wv, bv, vbuf, B_ * L_, D_, D_);
  // attention
  attn_kernel<<<dim3(L_ / 64, B_ * H_), blk, 0, stream>>>(qbuf, kbuf, vbuf, rel, attn);
  // FFN
  gemm_f32<1><<<dim3(DFC_ / 64, 64), blk, 0, stream>>>(attn, w1, b1, hid, B_ * L_, DFC_, D_);
  gemm_f32<0><<<dim3(D_ / 64, 64), blk, 0, stream>>>(hid, w2, b2, out, B_ * L_, D_, DFC_);
}

// Round 2
// 533.699 us; speedup vs baseline: 2.5733x; 2.5733x over previous
//
#include <hip/hip_runtime.h>
#include <cstdint>

#define B_   2
#define L_   2048
#define D_   512
#define H_   8
#define DH_  64
#define DFC_ 2048

typedef unsigned short ushort_t;
typedef __attribute__((ext_vector_type(8))) short bf16x8;
typedef __attribute__((ext_vector_type(4))) float f32x4;

#define MFMA16x16(A, Bv, C) __builtin_amdgcn_mfma_f32_16x16x32_bf16(A, Bv, C, 0, 0, 0)

__device__ __forceinline__ ushort_t f32_bf16(float f) {
  unsigned u = __float_as_uint(f);
  u += 0x7FFFu + ((u >> 16) & 1u);   // round-to-nearest-even
  return (ushort_t)(u >> 16);
}

// ---------------------------------------------------------------------------
// f32 tiled GEMM: C = A(MxK) @ B(KxN) + bias, 64x64 tile, 256 thr, 4x4/thread
// MODE 0: f32 out row-major; MODE 1: f32 +relu; MODE 3: bf16 scatter (B,H,L,DH)
// ---------------------------------------------------------------------------
template <int MODE>
__global__ __launch_bounds__(256)
void gemm_f32(const float* __restrict__ A, const float* __restrict__ Bw,
              const float* __restrict__ bias, float* __restrict__ C,
              int M, int N, int K) {
  __shared__ float As[16 * 68];   // A^T tile: As[kk][m]
  __shared__ float Bs[16 * 64];   // Bs[kk][n]
  const int t  = threadIdx.x;
  const int tx = t & 15, ty = t >> 4;
  const int n0 = blockIdx.x * 64, m0 = blockIdx.y * 64;

  float acc[4][4] = {};

  for (int k0 = 0; k0 < K; k0 += 16) {
    {
      const int kk = t & 15, mb = t >> 4;
#pragma unroll
      for (int it = 0; it < 4; ++it) {
        int m = mb + it * 16;
        As[kk * 68 + m] = A[(size_t)(m0 + m) * K + k0 + kk];
      }
    }
    {
      const int n = t & 63, kbase = t >> 6;
#pragma unroll
      for (int it = 0; it < 4; ++it) {
        int kk = kbase + it * 4;
        Bs[kk * 64 + n] = Bw[(size_t)(k0 + kk) * N + n0 + n];
      }
    }
    __syncthreads();
#pragma unroll
    for (int kk = 0; kk < 16; ++kk) {
      float4 av = *(const float4*)&As[kk * 68 + ty * 4];
      float4 bv = *(const float4*)&Bs[kk * 64 + tx * 4];
      float a[4] = {av.x, av.y, av.z, av.w};
      float b[4] = {bv.x, bv.y, bv.z, bv.w};
#pragma unroll
      for (int i = 0; i < 4; ++i)
#pragma unroll
        for (int j = 0; j < 4; ++j)
          acc[i][j] = fmaf(a[i], b[j], acc[i][j]);
    }
    __syncthreads();
  }

  if (MODE == 3) {
    // bf16 scatter to (B,H,L,DH)
    ushort_t* Cb = (ushort_t*)C;
    const int c = n0 + tx * 4;
    const int h = c >> 6, dh = c & 63;
    float b0 = bias[c], b1 = bias[c + 1], b2 = bias[c + 2], b3 = bias[c + 3];
#pragma unroll
    for (int i = 0; i < 4; ++i) {
      int r = m0 + ty * 4 + i;
      int b = r >> 11, l = r & (L_ - 1);
      ushort4 o;
      o.x = f32_bf16(acc[i][0] + b0);
      o.y = f32_bf16(acc[i][1] + b1);
      o.z = f32_bf16(acc[i][2] + b2);
      o.w = f32_bf16(acc[i][3] + b3);
      *(ushort4*)&Cb[((size_t)(b * H_ + h) * L_ + l) * DH_ + dh] = o;
    }
  } else {
    const float* bp = bias + n0 + tx * 4;
    float b0 = bp[0], b1 = bp[1], b2 = bp[2], b3 = bp[3];
#pragma unroll
    for (int i = 0; i < 4; ++i) {
      int r = m0 + ty * 4 + i;
      float4 o;
      o.x = acc[i][0] + b0; o.y = acc[i][1] + b1;
      o.z = acc[i][2] + b2; o.w = acc[i][3] + b3;
      if (MODE == 1) {
        o.x = fmaxf(o.x, 0.f); o.y = fmaxf(o.y, 0.f);
        o.z = fmaxf(o.z, 0.f); o.w = fmaxf(o.w, 0.f);
      }
      *(float4*)&C[(size_t)r * N + n0 + tx * 4] = o;
    }
  }
}

// ---------------------------------------------------------------------------
// rel_emb f32 (L,512) -> bf16 copy
// ---------------------------------------------------------------------------
__global__ __launch_bounds__(256)
void pack_rel(const float* __restrict__ r, ushort_t* __restrict__ o) {
  int i = (blockIdx.x * 256 + threadIdx.x) * 4;
  float4 f = *(const float4*)(r + i);
  ushort4 u;
  u.x = f32_bf16(f.x); u.y = f32_bf16(f.y);
  u.z = f32_bf16(f.z); u.w = f32_bf16(f.w);
  *(ushort4*)(o + i) = u;
}

// ---------------------------------------------------------------------------
// v f32 (B,L,D) -> bf16 transposed (B,H,DH,L)
// grid (L/64, B*H); 64(l) x 64(dh) tile via LDS transpose
// ---------------------------------------------------------------------------
__global__ __launch_bounds__(256)
void pack_vT(const float* __restrict__ vf, ushort_t* __restrict__ vT) {
  __shared__ float T[64 * 67];
  const int t = threadIdx.x;
  const int bh = blockIdx.y;
  const int b = bh >> 3, h = bh & 7;
  const int l0 = blockIdx.x * 64;
  {
    const int li = t >> 2, c0 = (t & 3) * 16;
    const float* src = vf + ((size_t)(b * L_) + l0 + li) * D_ + h * 64 + c0;
#pragma unroll
    for (int u = 0; u < 4; ++u) {
      float4 f = *(const float4*)(src + u * 4);
      T[li * 67 + c0 + u * 4 + 0] = f.x;
      T[li * 67 + c0 + u * 4 + 1] = f.y;
      T[li * 67 + c0 + u * 4 + 2] = f.z;
      T[li * 67 + c0 + u * 4 + 3] = f.w;
    }
  }
  __syncthreads();
  const int dh = t >> 2, g = t & 3;
  union { bf16x8 v; ushort_t s[8]; } o0, o1;
#pragma unroll
  for (int jj = 0; jj < 8; ++jj) {
    o0.s[jj] = f32_bf16(T[(g * 16 + jj) * 67 + dh]);
    o1.s[jj] = f32_bf16(T[(g * 16 + 8 + jj) * 67 + dh]);
  }
  ushort_t* dst = vT + ((size_t)bh * 64 + dh) * L_ + l0 + g * 16;
  *(bf16x8*)(dst) = o0.v;
  *(bf16x8*)(dst + 8) = o1.v;
}

// ---------------------------------------------------------------------------
// MFMA flash attention with relative-position skew.
// Grid (32, B*H); block = 256 thr = 4 waves; wave w owns q-rows [16w,16w+16).
// Per K-tile: S = Q@K^T (8 mfma) ; R_next = Q@E_chunk^T (8 mfma) ;
// skew-gather from 2-slot Rcat ring ; online softmax ; O += P@V (8 mfma).
// ---------------------------------------------------------------------------
__global__ __launch_bounds__(256, 2)
void attn_mfma(const ushort_t* __restrict__ q16, const ushort_t* __restrict__ k16,
               const ushort_t* __restrict__ vT, const ushort_t* __restrict__ relb,
               float* __restrict__ attn_out) {
  __shared__ ushort_t Ks[64 * 72];     // K tile rows [j][d], stride 72
  __shared__ ushort_t Vt[64 * 72];     // V^T tile rows [dh][j], stride 72
  __shared__ ushort_t Pst[64 * 72];    // P tile rows [i][j], stride 72
  __shared__ float Rcat[64 * 132];     // QE2 ring: [row][slot*66 + c], 2 slots

  const int t   = threadIdx.x;
  const int wv  = t >> 6;
  const int ln  = t & 63;
  const int l16 = ln & 15;
  const int lg  = ln >> 4;
  const int bh  = blockIdx.y;
  const int h   = bh & 7;
  const int b   = bh >> 3;
  const int qb  = (bh & 8) ? (31 - (int)blockIdx.x) : (int)blockIdx.x;
  const int i0  = qb * 64;

  const ushort_t* qh = q16 + (size_t)bh * L_ * DH_;
  const ushort_t* kh = k16 + (size_t)bh * L_ * DH_;
  const ushort_t* vh = vT + (size_t)bh * DH_ * L_;
  const ushort_t* relh = relb + h * 64;

  // Q A-frags (held in regs all loop): rows 16*wv + l16, k-groups {lg*8, 32+lg*8}
  bf16x8 qf0, qf1;
  {
    const ushort_t* qrow = qh + (size_t)(i0 + wv * 16 + l16) * DH_ + lg * 8;
    qf0 = *(const bf16x8*)(qrow);
    qf1 = *(const bf16x8*)(qrow + 32);
  }

  const f32x4 zf = {0.f, 0.f, 0.f, 0.f};
  f32x4 Of[4] = {zf, zf, zf, zf};
  float mrow[4] = {-3.0e38f, -3.0e38f, -3.0e38f, -3.0e38f};
  float lrow[4] = {0.f, 0.f, 0.f, 0.f};

  // compute QE2 chunk (64 cols starting at e-row mbase) into Rcat slot
  auto compute_R = [&](int mbase, int slot) {
#pragma unroll
    for (int cb = 0; cb < 4; ++cb) {
      int m = mbase + cb * 16 + l16;
      if (m > L_ - 1) m = L_ - 1;          // clamped rows feed masked cols only
      const ushort_t* ep = relh + (size_t)m * D_;
      bf16x8 e0 = *(const bf16x8*)(ep + lg * 8);
      bf16x8 e1 = *(const bf16x8*)(ep + 32 + lg * 8);
      f32x4 r = MFMA16x16(qf0, e0, zf);
      r = MFMA16x16(qf1, e1, r);
      int base = (wv * 16 + lg * 4) * 132 + slot * 66 + cb * 16 + l16;
      Rcat[base]           = r[0];
      Rcat[base + 132]     = r[1];
      Rcat[base + 264]     = r[2];
      Rcat[base + 396]     = r[3];
    }
  };

  compute_R(L_ - 64 - i0, 0);   // chunk 0 -> slot 0

  for (int kb = 0; kb <= qb; ++kb) {
    const int j0 = kb * 64;
    __syncthreads();   // prior iter's reads of Ks/Vt complete
    {
      // stage K tile and V^T tile: thread t handles rows (t>>3) and (t>>3)+32,
      // 16B chunk (t&7) -> fully coalesced 128B-per-row global reads
      const int j = t >> 3, c0 = (t & 7) * 8;
      *(bf16x8*)&Ks[j * 72 + c0] =
          *(const bf16x8*)(kh + (size_t)(j0 + j) * DH_ + c0);
      *(bf16x8*)&Ks[(j + 32) * 72 + c0] =
          *(const bf16x8*)(kh + (size_t)(j0 + j + 32) * DH_ + c0);
      *(bf16x8*)&Vt[j * 72 + c0] =
          *(const bf16x8*)(vh + (size_t)j * L_ + j0 + c0);
      *(bf16x8*)&Vt[(j + 32) * 72 + c0] =
          *(const bf16x8*)(vh + (size_t)(j + 32) * L_ + j0 + c0);
    }
    __syncthreads();

    // S = Q @ K^T
    f32x4 sf[4];
#pragma unroll
    for (int cb = 0; cb < 4; ++cb) {
      bf16x8 k0 = *(const bf16x8*)&Ks[(cb * 16 + l16) * 72 + lg * 8];
      bf16x8 k1 = *(const bf16x8*)&Ks[(cb * 16 + l16) * 72 + 32 + lg * 8];
      f32x4 s = MFMA16x16(qf0, k0, zf);
      sf[cb] = MFMA16x16(qf1, k1, s);
    }

    // R_next: chunk kb+1 (e-rows [L - i0 + j0, +64)) -> slot (kb+1)&1
    compute_R(L_ - i0 + j0, (kb + 1) & 1);

    // skew-gather + scale + causal mask
    float sv[4][4];
#pragma unroll
    for (int cb = 0; cb < 4; ++cb) {
      const int jj = cb * 16 + l16;
#pragma unroll
      for (int reg = 0; reg < 4; ++reg) {
        const int r64 = wv * 16 + lg * 4 + reg;
        const int cgl = jj + 63 - r64;                 // 0..126
        const int slot = (kb + (cgl >> 6)) & 1;
        float srel = Rcat[r64 * 132 + slot * 66 + (cgl & 63)];
        float x = (sf[cb][reg] + srel) * 0.125f;
        if (kb == qb && jj > r64) x = -1e30f;
        sv[cb][reg] = x;
      }
    }

    // online softmax (row stats per reg, reduced over the 16 lanes of a group)
#pragma unroll
    for (int reg = 0; reg < 4; ++reg) {
      float mx = fmaxf(fmaxf(sv[0][reg], sv[1][reg]), fmaxf(sv[2][reg], sv[3][reg]));
      mx = fmaxf(mx, __shfl_xor(mx, 1));
      mx = fmaxf(mx, __shfl_xor(mx, 2));
      mx = fmaxf(mx, __shfl_xor(mx, 4));
      mx = fmaxf(mx, __shfl_xor(mx, 8));
      float mnew = fmaxf(mrow[reg], mx);
      float alpha = __expf(mrow[reg] - mnew);
      mrow[reg] = mnew;
      float ssum = 0.f;
#pragma unroll
      for (int cb = 0; cb < 4; ++cb) {
        float p = __expf(sv[cb][reg] - mnew);
        sv[cb][reg] = p;
        ssum += p;
      }
      ssum += __shfl_xor(ssum, 1);
      ssum += __shfl_xor(ssum, 2);
      ssum += __shfl_xor(ssum, 4);
      ssum += __shfl_xor(ssum, 8);
      lrow[reg] = lrow[reg] * alpha + ssum;
#pragma unroll
      for (int cb = 0; cb < 4; ++cb) Of[cb][reg] *= alpha;
    }

    // P: C-layout regs -> LDS (own wave's rows only; in-order LDS pipe)
#pragma unroll
    for (int cb = 0; cb < 4; ++cb)
#pragma unroll
      for (int reg = 0; reg < 4; ++reg)
        Pst[(wv * 16 + lg * 4 + reg) * 72 + cb * 16 + l16] = f32_bf16(sv[cb][reg]);

    // O += P @ V
    bf16x8 pa0 = *(const bf16x8*)&Pst[(wv * 16 + l16) * 72 + lg * 8];
    bf16x8 pa1 = *(const bf16x8*)&Pst[(wv * 16 + l16) * 72 + 32 + lg * 8];
#pragma unroll
    for (int cb = 0; cb < 4; ++cb) {
      bf16x8 v0 = *(const bf16x8*)&Vt[(cb * 16 + l16) * 72 + lg * 8];
      bf16x8 v1 = *(const bf16x8*)&Vt[(cb * 16 + l16) * 72 + 32 + lg * 8];
      Of[cb] = MFMA16x16(pa0, v0, Of[cb]);
      Of[cb] = MFMA16x16(pa1, v1, Of[cb]);
    }
  }

  // epilogue: attn_out (B,L,D) f32, normalized
#pragma unroll
  for (int reg = 0; reg < 4; ++reg) {
    const int i = i0 + wv * 16 + lg * 4 + reg;
    float inv_l = 1.f / lrow[reg];
    float* orow = attn_out + ((size_t)(b * L_ + i)) * D_ + h * 64;
#pragma unroll
    for (int cb = 0; cb < 4; ++cb)
      orow[cb * 16 + l16] = Of[cb][reg] * inv_l;
  }
}

// ---------------------------------------------------------------------------
extern "C" void kernel_launch(void* const* d_in, const int* in_sizes, int n_in,
                              void* d_out, int out_size, void* d_ws, size_t ws_size,
                              hipStream_t stream) {
  const float* x   = (const float*)d_in[0];
  // d_in[1] = mask (unused; causal mask applied analytically)
  const float* wq  = (const float*)d_in[2];
  const float* bq  = (const float*)d_in[3];
  const float* wk  = (const float*)d_in[4];
  const float* bk  = (const float*)d_in[5];
  const float* wv  = (const float*)d_in[6];
  const float* bv  = (const float*)d_in[7];
  const float* rel = (const float*)d_in[8];
  const float* w1  = (const float*)d_in[9];
  const float* b1  = (const float*)d_in[10];
  const float* w2  = (const float*)d_in[11];
  const float* b2  = (const float*)d_in[12];

  char* wsb = (char*)d_ws;
  ushort_t* q16  = (ushort_t*)(wsb + 0);               // 4 MB (B,H,L,DH) bf16
  ushort_t* k16  = (ushort_t*)(wsb + (4u << 20));      // 4 MB
  ushort_t* vTb  = (ushort_t*)(wsb + (8u << 20));      // 4 MB (B,H,DH,L) bf16
  ushort_t* relb = (ushort_t*)(wsb + (12u << 20));     // 2 MB (L,D) bf16
  float*    vf32 = (float*)(wsb + (16u << 20));        // 8 MB (B,L,D) f32
  float*    attn = (float*)(wsb + (32u << 20));        // 8 MB (B,L,D) f32
  float*    hid  = (float*)(wsb + 0);                  // 32 MB, reuses [0,32MB) after attn
  float*    out  = (float*)d_out;

  dim3 blk(256);
  gemm_f32<3><<<dim3(8, 64), blk, 0, stream>>>(x, wq, bq, (float*)q16, B_ * L_, D_, D_);
  gemm_f32<3><<<dim3(8, 64), blk, 0, stream>>>(x, wk, bk, (float*)k16, B_ * L_, D_, D_);
  gemm_f32<0><<<dim3(8, 64), blk, 0, stream>>>(x, wv, bv, vf32, B_ * L_, D_, D_);
  pack_rel<<<dim3(1024), blk, 0, stream>>>(rel, relb);
  pack_vT<<<dim3(L_ / 64, B_ * H_), blk, 0, stream>>>(vf32, vTb);
  attn_mfma<<<dim3(32, B_ * H_), blk, 0, stream>>>(q16, k16, vTb, relb, attn);
  gemm_f32<1><<<dim3(DFC_ / 64, 64), blk, 0, stream>>>(attn, w1, b1, hid, B_ * L_, DFC_, D_);
  gemm_f32<0><<<dim3(D_ / 64, 64), blk, 0, stream>>>(hid, w2, b2, out, B_ * L_, D_, DFC_);
}

// Round 3
// 260.989 us; speedup vs baseline: 5.2621x; 2.0449x over previous
//
#include <hip/hip_runtime.h>
#include <cstdint>

#define B_   2
#define L_   2048
#define D_   512
#define H_   8
#define DH_  64
#define DFC_ 2048

typedef unsigned short ushort_t;
typedef __attribute__((ext_vector_type(8))) short bf16x8;
typedef __attribute__((ext_vector_type(4))) float f32x4;

#define MFMA16x16(A, Bv, C) __builtin_amdgcn_mfma_f32_16x16x32_bf16(A, Bv, C, 0, 0, 0)

__device__ __forceinline__ ushort_t f32_bf16(float f) {
  unsigned u = __float_as_uint(f);
  u += 0x7FFFu + ((u >> 16) & 1u);   // round-to-nearest-even
  return (ushort_t)(u >> 16);
}

__device__ __forceinline__ void gl_lds16(const ushort_t* g, ushort_t* l) {
  __builtin_amdgcn_global_load_lds(
      (const __attribute__((address_space(1))) void*)(const void*)g,
      (__attribute__((address_space(3))) void*)l, 16, 0, 0);
}

// ---------------------------------------------------------------------------
// f32 -> bf16 straight pack (n multiple of 2048)
// ---------------------------------------------------------------------------
__global__ __launch_bounds__(256)
void pack_bf16(const float* __restrict__ in, ushort_t* __restrict__ out) {
  int i = (blockIdx.x * 256 + threadIdx.x) * 8;
  float4 a = *(const float4*)(in + i);
  float4 b = *(const float4*)(in + i + 4);
  union { bf16x8 v; ushort_t s[8]; } u;
  u.s[0] = f32_bf16(a.x); u.s[1] = f32_bf16(a.y);
  u.s[2] = f32_bf16(a.z); u.s[3] = f32_bf16(a.w);
  u.s[4] = f32_bf16(b.x); u.s[5] = f32_bf16(b.y);
  u.s[6] = f32_bf16(b.z); u.s[7] = f32_bf16(b.w);
  *(bf16x8*)(out + i) = u.v;
}

// ---------------------------------------------------------------------------
// f32 (K,N) row-major -> bf16 (N,K) transposed. grid (N/64, K/64), 256 thr.
// ---------------------------------------------------------------------------
__global__ __launch_bounds__(256)
void packT(const float* __restrict__ in, ushort_t* __restrict__ out, int K, int N) {
  __shared__ float T[64 * 65];
  const int t = threadIdx.x;
  const int n0 = blockIdx.x * 64, k0 = blockIdx.y * 64;
  {
    const int kr = t >> 2, c0 = (t & 3) * 16;
    const float* src = in + (size_t)(k0 + kr) * N + n0 + c0;
#pragma unroll
    for (int u = 0; u < 4; ++u) {
      float4 f = *(const float4*)(src + u * 4);
      T[kr * 65 + c0 + u * 4 + 0] = f.x;
      T[kr * 65 + c0 + u * 4 + 1] = f.y;
      T[kr * 65 + c0 + u * 4 + 2] = f.z;
      T[kr * 65 + c0 + u * 4 + 3] = f.w;
    }
  }
  __syncthreads();
  const int nr = t >> 2, kc0 = (t & 3) * 16;
  union { bf16x8 v; ushort_t s[8]; } o0, o1;
#pragma unroll
  for (int j = 0; j < 8; ++j) {
    o0.s[j] = f32_bf16(T[(kc0 + j) * 65 + nr]);
    o1.s[j] = f32_bf16(T[(kc0 + 8 + j) * 65 + nr]);
  }
  ushort_t* dst = out + (size_t)(n0 + nr) * K + k0 + kc0;
  *(bf16x8*)dst = o0.v;
  *(bf16x8*)(dst + 8) = o1.v;
}

// ---------------------------------------------------------------------------
// v16 bf16 (B,H,L,DH) -> vT bf16 (B,H,DH,L). grid (L/64, B*H).
// ---------------------------------------------------------------------------
__global__ __launch_bounds__(256)
void pack_vT_b(const ushort_t* __restrict__ v16, ushort_t* __restrict__ vT) {
  __shared__ ushort_t T2[64 * 68];
  const int t = threadIdx.x;
  const int bh = blockIdx.y;
  const int l0 = blockIdx.x * 64;
  {
    const int lr = t >> 2, c0 = (t & 3) * 16;
    const ushort_t* src = v16 + ((size_t)bh * L_ + l0 + lr) * 64 + c0;
    *(bf16x8*)&T2[lr * 68 + c0] = *(const bf16x8*)src;
    *(bf16x8*)&T2[lr * 68 + c0 + 8] = *(const bf16x8*)(src + 8);
  }
  __syncthreads();
  const int dr = t >> 2, kc0 = (t & 3) * 16;
  union { bf16x8 v; ushort_t s[8]; } o0, o1;
#pragma unroll
  for (int j = 0; j < 8; ++j) {
    o0.s[j] = T2[(kc0 + j) * 68 + dr];
    o1.s[j] = T2[(kc0 + 8 + j) * 68 + dr];
  }
  ushort_t* dst = vT + ((size_t)bh * 64 + dr) * L_ + l0 + kc0;
  *(bf16x8*)dst = o0.v;
  *(bf16x8*)(dst + 8) = o1.v;
}

// ---------------------------------------------------------------------------
// MFMA GEMM: C = A(M,K) @ Bt(N,K)^T. 128x128 tile, BK=32, 4 waves, m97-style
// global_load_lds staging with XOR chunk swizzle (2-way bank aliasing only).
// MODE 0: f32 raw partial out (split-K via blockIdx.z: z==0 -> out0, z -> out1)
// MODE 1: bf16 out, +bias +relu
// MODE 2: QKV scatter: bf16 q/k/v (B,H,L,DH), per-range bias
// ---------------------------------------------------------------------------
template <int MODE>
__global__ __launch_bounds__(256, 2)
void gemm_mfma(const ushort_t* __restrict__ A, const ushort_t* __restrict__ Bt,
               const float* __restrict__ b0p, const float* __restrict__ b1p,
               const float* __restrict__ b2p,
               void* __restrict__ out0, void* __restrict__ out1, void* __restrict__ out2,
               int M, int N, int K, int ksplit) {
  __shared__ ushort_t As[128 * 32];
  __shared__ ushort_t Bs[128 * 32];

  const int t  = threadIdx.x;
  const int wv = t >> 6, ln = t & 63;
  const int l16 = ln & 15, lg = ln >> 4;
  const int n0 = blockIdx.x * 128, m0 = blockIdx.y * 128;
  const int mw = (wv >> 1) * 64, nw = (wv & 1) * 64;

  const int kchunk = K / ksplit;
  const int kbeg = blockIdx.z * kchunk, kend = kbeg + kchunk;

  f32x4 acc[4][4] = {};

  for (int k0 = kbeg; k0 < kend; k0 += 32) {
    __syncthreads();
#pragma unroll
    for (int i = 0; i < 2; ++i) {
      const int s = (i * 4 + wv) * 64 + ln;
      const int row = s >> 2, cs = s & 3;
      const int g = cs ^ ((row >> 1) & 3);
      gl_lds16(A + (size_t)(m0 + row) * K + k0 + g * 8, &As[(i * 4 + wv) * 512]);
      gl_lds16(Bt + (size_t)(n0 + row) * K + k0 + g * 8, &Bs[(i * 4 + wv) * 512]);
    }
    __syncthreads();

    bf16x8 af[4], bfr[4];
#pragma unroll
    for (int mi = 0; mi < 4; ++mi) {
      const int ri = mw + mi * 16 + l16;
      af[mi] = *(const bf16x8*)&As[ri * 32 + ((lg ^ ((ri >> 1) & 3)) * 8)];
    }
#pragma unroll
    for (int ni = 0; ni < 4; ++ni) {
      const int rj = nw + ni * 16 + l16;
      bfr[ni] = *(const bf16x8*)&Bs[rj * 32 + ((lg ^ ((rj >> 1) & 3)) * 8)];
    }
#pragma unroll
    for (int mi = 0; mi < 4; ++mi)
#pragma unroll
      for (int ni = 0; ni < 4; ++ni)
        acc[mi][ni] = MFMA16x16(af[mi], bfr[ni], acc[mi][ni]);
  }

  // epilogue; C row = m0+mw+mi*16+lg*4+reg, col = n0+nw+ni*16+l16
  if (MODE == 0) {
    float* outp = (blockIdx.z == 0) ? (float*)out0 : (float*)out1;
#pragma unroll
    for (int mi = 0; mi < 4; ++mi)
#pragma unroll
      for (int reg = 0; reg < 4; ++reg) {
        const int m = m0 + mw + mi * 16 + lg * 4 + reg;
#pragma unroll
        for (int ni = 0; ni < 4; ++ni) {
          const int c = n0 + nw + ni * 16 + l16;
          outp[(size_t)m * N + c] = acc[mi][ni][reg];
        }
      }
  } else if (MODE == 1) {
    ushort_t* outp = (ushort_t*)out0;
#pragma unroll
    for (int mi = 0; mi < 4; ++mi)
#pragma unroll
      for (int reg = 0; reg < 4; ++reg) {
        const int m = m0 + mw + mi * 16 + lg * 4 + reg;
#pragma unroll
        for (int ni = 0; ni < 4; ++ni) {
          const int c = n0 + nw + ni * 16 + l16;
          float v = acc[mi][ni][reg] + b0p[c];
          outp[(size_t)m * N + c] = f32_bf16(fmaxf(v, 0.f));
        }
      }
  } else {
#pragma unroll
    for (int mi = 0; mi < 4; ++mi)
#pragma unroll
      for (int reg = 0; reg < 4; ++reg) {
        const int m = m0 + mw + mi * 16 + lg * 4 + reg;
        const int b = m >> 11, l = m & (L_ - 1);
#pragma unroll
        for (int ni = 0; ni < 4; ++ni) {
          const int c = n0 + nw + ni * 16 + l16;
          const int which = c >> 9, cc = c & 511;
          const int h = cc >> 6, dh = cc & 63;
          const float* bias = (which == 0) ? b0p : (which == 1) ? b1p : b2p;
          ushort_t* dst = (ushort_t*)((which == 0) ? out0 : (which == 1) ? out1 : out2);
          dst[(((size_t)b * H_ + h) * L_ + l) * DH_ + dh] =
              f32_bf16(acc[mi][ni][reg] + bias[cc]);
        }
      }
  }
}

// ---------------------------------------------------------------------------
// FFN2 split-K combine: out = out + p1 + bias (deterministic)
// ---------------------------------------------------------------------------
__global__ __launch_bounds__(256)
void ffn2_add(float* __restrict__ out, const float* __restrict__ p1,
              const float* __restrict__ bias) {
  int i = (blockIdx.x * 256 + threadIdx.x) * 4;
  float4 a = *(const float4*)(out + i);
  float4 b = *(const float4*)(p1 + i);
  float4 bb = *(const float4*)(bias + (i & (D_ - 1)));
  a.x += b.x + bb.x; a.y += b.y + bb.y;
  a.z += b.z + bb.z; a.w += b.w + bb.w;
  *(float4*)(out + i) = a;
}

// ---------------------------------------------------------------------------
// MFMA flash attention with relative-position skew (unchanged from R2 except
// bf16 output). Grid (32, B*H); 4 waves; wave w owns q-rows [16w,16w+16).
// ---------------------------------------------------------------------------
__global__ __launch_bounds__(256, 2)
void attn_mfma(const ushort_t* __restrict__ q16, const ushort_t* __restrict__ k16,
               const ushort_t* __restrict__ vT, const ushort_t* __restrict__ relb,
               ushort_t* __restrict__ attn_out) {
  __shared__ ushort_t Ks[64 * 72];
  __shared__ ushort_t Vt[64 * 72];
  __shared__ ushort_t Pst[64 * 72];
  __shared__ float Rcat[64 * 132];

  const int t   = threadIdx.x;
  const int wv  = t >> 6;
  const int ln  = t & 63;
  const int l16 = ln & 15;
  const int lg  = ln >> 4;
  const int bh  = blockIdx.y;
  const int h   = bh & 7;
  const int b   = bh >> 3;
  const int qb  = (bh & 8) ? (31 - (int)blockIdx.x) : (int)blockIdx.x;
  const int i0  = qb * 64;

  const ushort_t* qh = q16 + (size_t)bh * L_ * DH_;
  const ushort_t* kh = k16 + (size_t)bh * L_ * DH_;
  const ushort_t* vh = vT + (size_t)bh * DH_ * L_;
  const ushort_t* relh = relb + h * 64;

  bf16x8 qf0, qf1;
  {
    const ushort_t* qrow = qh + (size_t)(i0 + wv * 16 + l16) * DH_ + lg * 8;
    qf0 = *(const bf16x8*)(qrow);
    qf1 = *(const bf16x8*)(qrow + 32);
  }

  const f32x4 zf = {0.f, 0.f, 0.f, 0.f};
  f32x4 Of[4] = {zf, zf, zf, zf};
  float mrow[4] = {-3.0e38f, -3.0e38f, -3.0e38f, -3.0e38f};
  float lrow[4] = {0.f, 0.f, 0.f, 0.f};

  auto compute_R = [&](int mbase, int slot) {
#pragma unroll
    for (int cb = 0; cb < 4; ++cb) {
      int m = mbase + cb * 16 + l16;
      if (m > L_ - 1) m = L_ - 1;
      const ushort_t* ep = relh + (size_t)m * D_;
      bf16x8 e0 = *(const bf16x8*)(ep + lg * 8);
      bf16x8 e1 = *(const bf16x8*)(ep + 32 + lg * 8);
      f32x4 r = MFMA16x16(qf0, e0, zf);
      r = MFMA16x16(qf1, e1, r);
      int base = (wv * 16 + lg * 4) * 132 + slot * 66 + cb * 16 + l16;
      Rcat[base]       = r[0];
      Rcat[base + 132] = r[1];
      Rcat[base + 264] = r[2];
      Rcat[base + 396] = r[3];
    }
  };

  compute_R(L_ - 64 - i0, 0);

  for (int kb = 0; kb <= qb; ++kb) {
    const int j0 = kb * 64;
    __syncthreads();
    {
      const int j = t >> 3, c0 = (t & 7) * 8;
      *(bf16x8*)&Ks[j * 72 + c0] =
          *(const bf16x8*)(kh + (size_t)(j0 + j) * DH_ + c0);
      *(bf16x8*)&Ks[(j + 32) * 72 + c0] =
          *(const bf16x8*)(kh + (size_t)(j0 + j + 32) * DH_ + c0);
      *(bf16x8*)&Vt[j * 72 + c0] =
          *(const bf16x8*)(vh + (size_t)j * L_ + j0 + c0);
      *(bf16x8*)&Vt[(j + 32) * 72 + c0] =
          *(const bf16x8*)(vh + (size_t)(j + 32) * L_ + j0 + c0);
    }
    __syncthreads();

    f32x4 sf[4];
#pragma unroll
    for (int cb = 0; cb < 4; ++cb) {
      bf16x8 k0 = *(const bf16x8*)&Ks[(cb * 16 + l16) * 72 + lg * 8];
      bf16x8 k1 = *(const bf16x8*)&Ks[(cb * 16 + l16) * 72 + 32 + lg * 8];
      f32x4 s = MFMA16x16(qf0, k0, zf);
      sf[cb] = MFMA16x16(qf1, k1, s);
    }

    compute_R(L_ - i0 + j0, (kb + 1) & 1);

    float sv[4][4];
#pragma unroll
    for (int cb = 0; cb < 4; ++cb) {
      const int jj = cb * 16 + l16;
#pragma unroll
      for (int reg = 0; reg < 4; ++reg) {
        const int r64 = wv * 16 + lg * 4 + reg;
        const int cgl = jj + 63 - r64;
        const int slot = (kb + (cgl >> 6)) & 1;
        float srel = Rcat[r64 * 132 + slot * 66 + (cgl & 63)];
        float x = (sf[cb][reg] + srel) * 0.125f;
        if (kb == qb && jj > r64) x = -1e30f;
        sv[cb][reg] = x;
      }
    }

#pragma unroll
    for (int reg = 0; reg < 4; ++reg) {
      float mx = fmaxf(fmaxf(sv[0][reg], sv[1][reg]), fmaxf(sv[2][reg], sv[3][reg]));
      mx = fmaxf(mx, __shfl_xor(mx, 1));
      mx = fmaxf(mx, __shfl_xor(mx, 2));
      mx = fmaxf(mx, __shfl_xor(mx, 4));
      mx = fmaxf(mx, __shfl_xor(mx, 8));
      float mnew = fmaxf(mrow[reg], mx);
      float alpha = __expf(mrow[reg] - mnew);
      mrow[reg] = mnew;
      float ssum = 0.f;
#pragma unroll
      for (int cb = 0; cb < 4; ++cb) {
        float p = __expf(sv[cb][reg] - mnew);
        sv[cb][reg] = p;
        ssum += p;
      }
      ssum += __shfl_xor(ssum, 1);
      ssum += __shfl_xor(ssum, 2);
      ssum += __shfl_xor(ssum, 4);
      ssum += __shfl_xor(ssum, 8);
      lrow[reg] = lrow[reg] * alpha + ssum;
#pragma unroll
      for (int cb = 0; cb < 4; ++cb) Of[cb][reg] *= alpha;
    }

#pragma unroll
    for (int cb = 0; cb < 4; ++cb)
#pragma unroll
      for (int reg = 0; reg < 4; ++reg)
        Pst[(wv * 16 + lg * 4 + reg) * 72 + cb * 16 + l16] = f32_bf16(sv[cb][reg]);

    bf16x8 pa0 = *(const bf16x8*)&Pst[(wv * 16 + l16) * 72 + lg * 8];
    bf16x8 pa1 = *(const bf16x8*)&Pst[(wv * 16 + l16) * 72 + 32 + lg * 8];
#pragma unroll
    for (int cb = 0; cb < 4; ++cb) {
      bf16x8 v0 = *(const bf16x8*)&Vt[(cb * 16 + l16) * 72 + lg * 8];
      bf16x8 v1 = *(const bf16x8*)&Vt[(cb * 16 + l16) * 72 + 32 + lg * 8];
      Of[cb] = MFMA16x16(pa0, v0, Of[cb]);
      Of[cb] = MFMA16x16(pa1, v1, Of[cb]);
    }
  }

#pragma unroll
  for (int reg = 0; reg < 4; ++reg) {
    const int i = i0 + wv * 16 + lg * 4 + reg;
    float inv_l = 1.f / lrow[reg];
    ushort_t* orow = attn_out + ((size_t)(b * L_ + i)) * D_ + h * 64;
#pragma unroll
    for (int cb = 0; cb < 4; ++cb)
      orow[cb * 16 + l16] = f32_bf16(Of[cb][reg] * inv_l);
  }
}

// ---------------------------------------------------------------------------
extern "C" void kernel_launch(void* const* d_in, const int* in_sizes, int n_in,
                              void* d_out, int out_size, void* d_ws, size_t ws_size,
                              hipStream_t stream) {
  const float* x   = (const float*)d_in[0];
  const float* wq  = (const float*)d_in[2];
  const float* bq  = (const float*)d_in[3];
  const float* wk  = (const float*)d_in[4];
  const float* bk  = (const float*)d_in[5];
  const float* wv  = (const float*)d_in[6];
  const float* bv  = (const float*)d_in[7];
  const float* rel = (const float*)d_in[8];
  const float* w1  = (const float*)d_in[9];
  const float* b1  = (const float*)d_in[10];
  const float* w2  = (const float*)d_in[11];
  const float* b2  = (const float*)d_in[12];

  char* wsb = (char*)d_ws;
  const size_t MB = 1u << 20;
  ushort_t* xb     = (ushort_t*)(wsb + 0 * MB);    // 4 MB (M,K) bf16
  ushort_t* wqkvT  = (ushort_t*)(wsb + 4 * MB);    // 1.5 MB (1536,512) bf16
  ushort_t* w1T    = (ushort_t*)(wsb + 6 * MB);    // 2 MB (2048,512) bf16
  ushort_t* w2T    = (ushort_t*)(wsb + 8 * MB);    // 2 MB (512,2048) bf16
  ushort_t* relb   = (ushort_t*)(wsb + 10 * MB);   // 2 MB (2048,512) bf16
  ushort_t* q16    = (ushort_t*)(wsb + 12 * MB);   // 4 MB (B,H,L,DH)
  ushort_t* k16    = (ushort_t*)(wsb + 16 * MB);   // 4 MB
  ushort_t* v16    = (ushort_t*)(wsb + 20 * MB);   // 4 MB
  ushort_t* vTb    = (ushort_t*)(wsb + 24 * MB);   // 4 MB (B,H,DH,L)
  ushort_t* attnb  = (ushort_t*)(wsb + 28 * MB);   // 4 MB (B,L,D) bf16
  ushort_t* hidb   = (ushort_t*)(wsb + 12 * MB);   // 16 MB, aliases dead q/k/v/vT
  float*    p1     = (float*)(wsb + 0 * MB);       // 8 MB FFN2 split-K partial
  float*    out    = (float*)d_out;

  dim3 blk(256);
  // packs
  pack_bf16<<<dim3(1024), blk, 0, stream>>>(x, xb);                    // 2M elems
  pack_bf16<<<dim3(512), blk, 0, stream>>>(rel, relb);                 // 1M elems
  packT<<<dim3(8, 8), blk, 0, stream>>>(wq, wqkvT, 512, 512);
  packT<<<dim3(8, 8), blk, 0, stream>>>(wk, wqkvT + 512 * 512, 512, 512);
  packT<<<dim3(8, 8), blk, 0, stream>>>(wv, wqkvT + 2 * 512 * 512, 512, 512);
  packT<<<dim3(32, 8), blk, 0, stream>>>(w1, w1T, 512, 2048);
  packT<<<dim3(8, 32), blk, 0, stream>>>(w2, w2T, 2048, 512);
  // fused QKV projection (N=1536), scatter epilogue
  gemm_mfma<2><<<dim3(12, 32), blk, 0, stream>>>(
      xb, wqkvT, bq, bk, bv, q16, k16, v16, B_ * L_, 1536, D_, 1);
  pack_vT_b<<<dim3(32, 16), blk, 0, stream>>>(v16, vTb);
  // attention
  attn_mfma<<<dim3(32, B_ * H_), blk, 0, stream>>>(q16, k16, vTb, relb, attnb);
  // FFN1: bf16 out + relu
  gemm_mfma<1><<<dim3(16, 32), blk, 0, stream>>>(
      attnb, w1T, b1, nullptr, nullptr, hidb, nullptr, nullptr,
      B_ * L_, DFC_, D_, 1);
  // FFN2: split-K=2 -> d_out (z=0) and p1 (z=1), then combine with bias
  gemm_mfma<0><<<dim3(4, 32, 2), blk, 0, stream>>>(
      hidb, w2T, nullptr, nullptr, nullptr, out, p1, nullptr,
      B_ * L_, D_, DFC_, 2);
  ffn2_add<<<dim3(2048), blk, 0, stream>>>(out, p1, b2);
}